// Round 1
// baseline (545.887 us; speedup 1.0000x reference)
//
#include <hip/hip_runtime.h>
#include <math.h>

// MarginDevianceLoss: N=4096 rows, D=256, K=8 instances/class, targets = i/8.
// Outputs: [loss, prec, pos_d, neg_d] fp32.
//
// Pass 1: row_sum / row_sumsq over ALL j (no masking; neg stats derived by
//         subtracting the 7 pos entries + self, which are recomputed cheaply).
// Row stats: 8 class dots per row -> inter, thresh=pos_min-0.05, pos_loss.
// Pass 2: recompute sim, filter (diff class && s > thresh), softplus sums.
// Finalize: scalar reduction -> d_out[0..3].

#define NROWS 4096
#define DIM   256
#define KCLS  8

constexpr int BI = 32;          // rows per block
constexpr int BJ = 128;         // cols per j-tile
constexpr int KC = 32;          // k-chunk staged per B tile
constexpr int JSLICES = 4;      // grid.y: j-range splits (occupancy)
constexpr int JSLICE = NROWS / JSLICES;   // 1024 cols per block

__device__ __forceinline__ float softplus_f(float z) {
    // log(1+exp(z)), stable
    return fmaxf(z, 0.f) + log1pf(expf(-fabsf(z)));
}

// PASS 1: accumulate row_sum, row_sumsq (unmasked).
// PASS 2: accumulate cnt, neg-loss softplus sum with hard-negative filter.
template<int PASS>
__global__ __launch_bounds__(256)
void sim_pass_kernel(const float* __restrict__ X,
                     float* __restrict__ rowSum,
                     float* __restrict__ rowSumSq,
                     const float* __restrict__ interA,
                     const float* __restrict__ threshA,
                     float* __restrict__ nlsA,
                     int* __restrict__ cntA)
{
    // A^T: [k][i], padded to 36 for 16B-aligned float4 reads + conflict break
    __shared__ __align__(16) float At[DIM][BI + 4];   // 36 KB
    __shared__ __align__(16) float Bt[KC][BJ + 4];    // 16.5 KB  -> 3 blocks/CU

    const int t = threadIdx.x;
    const int ibase = blockIdx.x * BI;
    const int jslice0 = blockIdx.y * JSLICE;
    const float4* X4 = reinterpret_cast<const float4*>(X);

    // ---- stage A^T (32 rows x 256 k), coalesced float4 global reads ----
    #pragma unroll
    for (int p = 0; p < (BI * DIM / 4) / 256; ++p) {   // 8 iters
        int idx = t + p * 256;
        int row = idx >> 6;        // 64 float4 per row
        int c4  = idx & 63;
        float4 v = X4[(size_t)(ibase + row) * (DIM / 4) + c4];
        At[4 * c4 + 0][row] = v.x;
        At[4 * c4 + 1][row] = v.y;
        At[4 * c4 + 2][row] = v.z;
        At[4 * c4 + 3][row] = v.w;
    }
    // (first __syncthreads below fences this before any At read)

    const int ig = (t >> 5) * 4;   // this thread's 4 rows  (8 groups x 4 = 32)
    const int jg = (t & 31) * 4;   // this thread's 4 cols  (32 groups x 4 = 128)

    float sI[4]  = {0.f, 0.f, 0.f, 0.f};
    float sqI[4] = {0.f, 0.f, 0.f, 0.f};
    float interR[4], threshR[4];
    int   cntR[4] = {0, 0, 0, 0};
    float nlsR[4] = {0.f, 0.f, 0.f, 0.f};
    if constexpr (PASS == 2) {
        #pragma unroll
        for (int ii = 0; ii < 4; ++ii) {
            interR[ii]  = interA[ibase + ig + ii];
            threshR[ii] = threshA[ibase + ig + ii];
        }
    }

    for (int jt = 0; jt < JSLICE / BJ; ++jt) {         // 8 j-tiles
        const int jbase = jslice0 + jt * BJ;
        float acc[4][4] = {};
        for (int kc0 = 0; kc0 < DIM; kc0 += KC) {      // 8 k-chunks
            __syncthreads();   // protect Bt from previous chunk's readers
            // ---- stage B^T chunk: 128 cols x 32 k ----
            #pragma unroll
            for (int p = 0; p < (BJ * KC / 4) / 256; ++p) {   // 4 iters
                int idx = t + p * 256;
                int jj  = idx >> 3;      // 8 float4 per (row, 32-k) chunk
                int c4  = idx & 7;
                float4 v = X4[(size_t)(jbase + jj) * (DIM / 4) + (kc0 >> 2) + c4];
                Bt[4 * c4 + 0][jj] = v.x;
                Bt[4 * c4 + 1][jj] = v.y;
                Bt[4 * c4 + 2][jj] = v.z;
                Bt[4 * c4 + 3][jj] = v.w;
            }
            __syncthreads();
            #pragma unroll
            for (int kc = 0; kc < KC; ++kc) {
                float4 a = *reinterpret_cast<const float4*>(&At[kc0 + kc][ig]);
                float4 b = *reinterpret_cast<const float4*>(&Bt[kc][jg]);
                acc[0][0] = fmaf(a.x, b.x, acc[0][0]);
                acc[0][1] = fmaf(a.x, b.y, acc[0][1]);
                acc[0][2] = fmaf(a.x, b.z, acc[0][2]);
                acc[0][3] = fmaf(a.x, b.w, acc[0][3]);
                acc[1][0] = fmaf(a.y, b.x, acc[1][0]);
                acc[1][1] = fmaf(a.y, b.y, acc[1][1]);
                acc[1][2] = fmaf(a.y, b.z, acc[1][2]);
                acc[1][3] = fmaf(a.y, b.w, acc[1][3]);
                acc[2][0] = fmaf(a.z, b.x, acc[2][0]);
                acc[2][1] = fmaf(a.z, b.y, acc[2][1]);
                acc[2][2] = fmaf(a.z, b.z, acc[2][2]);
                acc[2][3] = fmaf(a.z, b.w, acc[2][3]);
                acc[3][0] = fmaf(a.w, b.x, acc[3][0]);
                acc[3][1] = fmaf(a.w, b.y, acc[3][1]);
                acc[3][2] = fmaf(a.w, b.z, acc[3][2]);
                acc[3][3] = fmaf(a.w, b.w, acc[3][3]);
            }
        }
        // ---- epilogue for this j-tile ----
        #pragma unroll
        for (int ii = 0; ii < 4; ++ii) {
            #pragma unroll
            for (int jj = 0; jj < 4; ++jj) {
                float s = acc[ii][jj];
                if constexpr (PASS == 1) {
                    sI[ii]  += s;
                    sqI[ii] += s * s;
                } else {
                    int i = ibase + ig + ii;
                    int j = jbase + jg + jj;
                    // negative (different class) && hard-negative filter
                    if (((i ^ j) >> 3) != 0 && s > threshR[ii]) {
                        cntR[ii]++;
                        nlsR[ii] += softplus_f(40.f * (s - interR[ii]));
                    }
                }
            }
        }
    }

    if constexpr (PASS == 1) {
        #pragma unroll
        for (int ii = 0; ii < 4; ++ii) {
            atomicAdd(&rowSum[ibase + ig + ii], sI[ii]);
            atomicAdd(&rowSumSq[ibase + ig + ii], sqI[ii]);
        }
    } else {
        #pragma unroll
        for (int ii = 0; ii < 4; ++ii) {
            if (cntR[ii] > 0) {
                atomicAdd(&cntA[ibase + ig + ii], cntR[ii]);
                atomicAdd(&nlsA[ibase + ig + ii], nlsR[ii]);
            }
        }
    }
}

// Per-row: 8 class dots -> pos stats, neg stats by subtraction, inter,
// thresh = pos_min - 0.05, pos_loss. Also pos/neg grand totals.
__global__ __launch_bounds__(256)
void row_stats_kernel(const float* __restrict__ X,
                      const float* __restrict__ rowSum,
                      const float* __restrict__ rowSumSq,
                      float* __restrict__ interA,
                      float* __restrict__ threshA,
                      float* __restrict__ posLossA,
                      float* __restrict__ accum)
{
    const int i = blockIdx.x * blockDim.x + threadIdx.x;   // 4096 threads
    const float4* X4 = reinterpret_cast<const float4*>(X);
    const int cb = (i >> 3) << 3;     // class base row
    const int self = i & 7;

    float acc[KCLS] = {};
    for (int q = 0; q < DIM / 4; ++q) {
        float4 xi = X4[(size_t)i * (DIM / 4) + q];
        #pragma unroll
        for (int m = 0; m < KCLS; ++m) {
            float4 xm = X4[(size_t)(cb + m) * (DIM / 4) + q];
            acc[m] = fmaf(xi.x, xm.x, acc[m]);
            acc[m] = fmaf(xi.y, xm.y, acc[m]);
            acc[m] = fmaf(xi.z, xm.z, acc[m]);
            acc[m] = fmaf(xi.w, xm.w, acc[m]);
        }
    }

    float sii = acc[self];
    float psum = 0.f, psq = 0.f, pmin = 1e30f;
    #pragma unroll
    for (int m = 0; m < KCLS; ++m) {
        if (m != self) {
            psum += acc[m];
            psq  += acc[m] * acc[m];
            pmin  = fminf(pmin, acc[m]);
        }
    }
    const float p = (float)(KCLS - 1);            // 7
    const float mneg = (float)(NROWS - KCLS);     // 4088
    float nsum = rowSum[i] - psum - sii;
    float nsq  = rowSumSq[i] - psq - sii * sii;
    float pmean = psum / p;
    float pstd  = sqrtf(fmaxf(psq / p - pmean * pmean, 0.f));
    float nmean = nsum / mneg;
    float nstd  = sqrtf(fmaxf(nsq / mneg - nmean * nmean, 0.f));
    float inter = 0.8f * (nstd * pmean + pstd * nmean) / (pstd + nstd) + 0.1f;

    float pl = 0.f;
    #pragma unroll
    for (int m = 0; m < KCLS; ++m) {
        if (m != self) pl += softplus_f(-10.f * (acc[m] - inter));
    }
    pl *= 0.2f / p;

    interA[i]   = inter;
    threshA[i]  = pmin - 0.05f;
    posLossA[i] = pl;

    // wave-reduce the grand totals, one atomic per wave
    float w0 = psum, w1 = nsum;
    #pragma unroll
    for (int off = 32; off > 0; off >>= 1) {
        w0 += __shfl_down(w0, off);
        w1 += __shfl_down(w1, off);
    }
    if ((threadIdx.x & 63) == 0) {
        atomicAdd(&accum[0], w0);
        atomicAdd(&accum[1], w1);
    }
}

__global__ __launch_bounds__(256)
void finalize_kernel(const float* __restrict__ posLossA,
                     const float* __restrict__ nlsA,
                     const int* __restrict__ cntA,
                     const float* __restrict__ accum,
                     float* __restrict__ out)
{
    const int t = threadIdx.x;
    float loss = 0.f, inv = 0.f;
    for (int r = t; r < NROWS; r += 256) {
        int c = cntA[r];
        if (c > 0) loss += posLossA[r] + 0.05f * nlsA[r] / (float)c;
        else inv += 1.f;
    }
    #pragma unroll
    for (int off = 32; off > 0; off >>= 1) {
        loss += __shfl_down(loss, off);
        inv  += __shfl_down(inv, off);
    }
    __shared__ float sl[4], si[4];
    int w = t >> 6;
    if ((t & 63) == 0) { sl[w] = loss; si[w] = inv; }
    __syncthreads();
    if (t == 0) {
        float L = sl[0] + sl[1] + sl[2] + sl[3];
        float I = si[0] + si[1] + si[2] + si[3];
        out[0] = L / (float)NROWS;
        out[1] = I / (float)NROWS;
        out[2] = accum[0] / ((float)NROWS * (float)(KCLS - 1));
        out[3] = accum[1] / ((float)NROWS * (float)(NROWS - KCLS));
    }
}

extern "C" void kernel_launch(void* const* d_in, const int* in_sizes, int n_in,
                              void* d_out, int out_size, void* d_ws, size_t ws_size,
                              hipStream_t stream)
{
    const float* X = (const float*)d_in[0];
    // (targets = arange//8 by construction; class structure used directly)

    float* ws       = (float*)d_ws;
    float* accum    = ws;                    // 8 floats
    float* rowSum   = ws + 8;                // 4096
    float* rowSumSq = ws + 8 + NROWS;        // 4096
    float* nlsA     = ws + 8 + 2 * NROWS;    // 4096
    int*   cntA     = (int*)(ws + 8 + 3 * NROWS);  // 4096
    float* interA   = ws + 8 + 4 * NROWS;    // 4096
    float* threshA  = ws + 8 + 5 * NROWS;    // 4096
    float* posLossA = ws + 8 + 6 * NROWS;    // 4096
    // total ws use: (8 + 7*4096)*4 B = ~115 KB

    // zero the atomic-accumulated region: accum + rowSum + rowSumSq + nls + cnt
    hipMemsetAsync(d_ws, 0, (8 + 4 * NROWS) * sizeof(float), stream);

    dim3 grid(NROWS / BI, JSLICES);   // 128 x 4 = 512 blocks
    sim_pass_kernel<1><<<grid, 256, 0, stream>>>(X, rowSum, rowSumSq,
                                                 nullptr, nullptr, nullptr, nullptr);
    row_stats_kernel<<<NROWS / 256, 256, 0, stream>>>(X, rowSum, rowSumSq,
                                                      interA, threshA, posLossA, accum);
    sim_pass_kernel<2><<<grid, 256, 0, stream>>>(X, rowSum, rowSumSq,
                                                 interA, threshA, nlsA, cntA);
    finalize_kernel<<<1, 256, 0, stream>>>(posLossA, nlsA, cntA, accum, (float*)d_out);
}

// Round 3
// 172.857 us; speedup vs baseline: 3.1580x; 3.1580x over previous
//
#include <hip/hip_runtime.h>
#include <math.h>

// MarginDevianceLoss: N=4096 rows, D=256, K=8 instances/class, targets = i/8.
// Outputs: [loss, prec, pos_d, neg_d] fp32.
//
// R3: sim passes via bf16 MFMA (16x16x32), fragments loaded directly from
// global (X_bf16 = 2 MB, L2-resident); no LDS at all. Pos stats / inter /
// thresh stay fp32 (row_stats kernel). Neg stats derived by subtraction.
// (R2 -> R3: __exp2f/__log2f CUDA-isms replaced with __builtin_exp2f/log2f.)

#define NROWS 4096
#define DIM   256
#define KCLS  8

typedef __bf16 bf16x8 __attribute__((ext_vector_type(8)));
typedef float  f32x4  __attribute__((ext_vector_type(4)));

__device__ __forceinline__ float softplus_fast(float z) {
    // log(1+exp(z)), stable; v_exp_f32/v_log_f32 (~2^-21 rel err, plenty here)
    float m = fmaxf(z, 0.f);
    float e = __builtin_exp2f(-fabsf(z) * 1.4426950408889634f);
    return m + 0.6931471805599453f * __builtin_log2f(1.f + e);
}

__device__ __forceinline__ unsigned int pack_bf2(float a, float b) {
    unsigned int ua = __float_as_uint(a);
    unsigned int ub = __float_as_uint(b);
    ua = (ua + 0x7FFFu + ((ua >> 16) & 1u)) >> 16;   // RNE
    ub = (ub + 0x7FFFu + ((ub >> 16) & 1u)) >> 16;
    return ua | (ub << 16);
}

__global__ __launch_bounds__(256)
void convert_kernel(const float* __restrict__ X, unsigned short* __restrict__ Xb)
{
    int t = blockIdx.x * 256 + threadIdx.x;          // 131072 threads x 8 elems
    const float4* X4 = reinterpret_cast<const float4*>(X);
    float4 v0 = X4[2 * t];
    float4 v1 = X4[2 * t + 1];
    uint4 o;
    o.x = pack_bf2(v0.x, v0.y);
    o.y = pack_bf2(v0.z, v0.w);
    o.z = pack_bf2(v1.x, v1.y);
    o.w = pack_bf2(v1.z, v1.w);
    reinterpret_cast<uint4*>(Xb)[t] = o;
}

// Each wave: 2 i-tiles (32 rows, A register-cached for full K=256) x one
// 256-col j-slice (16 j-tiles). Grid (128, 4), 4 waves/block -> 16 j-slices.
// PASS 1: row sum / sumsq (unmasked).  PASS 2: hard-neg filter + softplus.
template<int PASS>
__global__ __launch_bounds__(256)
void sim_mfma_kernel(const unsigned short* __restrict__ Xb,
                     float* __restrict__ rowSum,
                     float* __restrict__ rowSumSq,
                     const float* __restrict__ interA,
                     const float* __restrict__ threshA,
                     float* __restrict__ nlsA,
                     int* __restrict__ cntA)
{
    const int lane = threadIdx.x & 63;
    const int wave = threadIdx.x >> 6;
    const int quad = lane >> 4;
    const int n16  = lane & 15;
    const int i0   = blockIdx.x * 32;
    const int j0   = (blockIdx.y * 4 + wave) * 256;

    // ---- A fragments: 2 i-tiles x 8 k-frags, straight from global ----
    // A[m=lane&15][k=quad*8+e]  -> 16 B contiguous per lane
    bf16x8 afrag[2][8];
    #pragma unroll
    for (int t = 0; t < 2; ++t) {
        const unsigned short* ap = Xb + (size_t)(i0 + t * 16 + n16) * DIM + quad * 8;
        #pragma unroll
        for (int kf = 0; kf < 8; ++kf)
            afrag[t][kf] = *reinterpret_cast<const bf16x8*>(ap + kf * 32);
    }

    float sI[2][4]  = {};
    float sqI[2][4] = {};
    int   cnt[2][4] = {};
    float nls[2][4] = {};
    float interR[2][4], threshR[2][4];
    if constexpr (PASS == 2) {
        #pragma unroll
        for (int t = 0; t < 2; ++t)
            #pragma unroll
            for (int r = 0; r < 4; ++r) {
                int i = i0 + t * 16 + quad * 4 + r;
                interR[t][r]  = interA[i];
                threshR[t][r] = threshA[i];
            }
    }

    for (int jt = 0; jt < 16; ++jt) {
        // B[k=quad*8+e][n=lane&15] = X[j0+jt*16+n16][k] -> same contiguous form
        const unsigned short* bp = Xb + (size_t)(j0 + jt * 16 + n16) * DIM + quad * 8;
        bf16x8 bfrag[8];
        #pragma unroll
        for (int kf = 0; kf < 8; ++kf)
            bfrag[kf] = *reinterpret_cast<const bf16x8*>(bp + kf * 32);

        f32x4 ac[2] = {{0.f, 0.f, 0.f, 0.f}, {0.f, 0.f, 0.f, 0.f}};
        #pragma unroll
        for (int kf = 0; kf < 8; ++kf) {
            ac[0] = __builtin_amdgcn_mfma_f32_16x16x32_bf16(afrag[0][kf], bfrag[kf], ac[0], 0, 0, 0);
            ac[1] = __builtin_amdgcn_mfma_f32_16x16x32_bf16(afrag[1][kf], bfrag[kf], ac[1], 0, 0, 0);
        }

        // C/D: col = lane&15, row = quad*4 + reg  (i from A rows, j from B cols)
        #pragma unroll
        for (int t = 0; t < 2; ++t) {
            #pragma unroll
            for (int r = 0; r < 4; ++r) {
                float s = ac[t][r];
                if constexpr (PASS == 1) {
                    sI[t][r]  += s;
                    sqI[t][r] += s * s;
                } else {
                    int i = i0 + t * 16 + quad * 4 + r;
                    int j = j0 + jt * 16 + n16;
                    if (((i ^ j) >> 3) != 0 && s > threshR[t][r]) {
                        cnt[t][r] += 1;
                        nls[t][r] += softplus_fast(40.f * (s - interR[t][r]));
                    }
                }
            }
        }
    }

    // ---- reduce across the 16 lanes of each quad (same rows), then atomics ----
    #pragma unroll
    for (int t = 0; t < 2; ++t) {
        #pragma unroll
        for (int r = 0; r < 4; ++r) {
            if constexpr (PASS == 1) {
                float a = sI[t][r], b = sqI[t][r];
                #pragma unroll
                for (int m = 8; m >= 1; m >>= 1) {
                    a += __shfl_xor(a, m);
                    b += __shfl_xor(b, m);
                }
                if (n16 == 0) {
                    int i = i0 + t * 16 + quad * 4 + r;
                    atomicAdd(&rowSum[i], a);
                    atomicAdd(&rowSumSq[i], b);
                }
            } else {
                int   c = cnt[t][r];
                float v = nls[t][r];
                #pragma unroll
                for (int m = 8; m >= 1; m >>= 1) {
                    c += __shfl_xor(c, m);
                    v += __shfl_xor(v, m);
                }
                if (n16 == 0) {
                    int i = i0 + t * 16 + quad * 4 + r;
                    if (c) {
                        atomicAdd(&cntA[i], c);
                        atomicAdd(&nlsA[i], v);
                    }
                }
            }
        }
    }
}

// Per-row fp32: 8 class dots -> pos stats, neg stats by subtraction, inter,
// thresh = pos_min - 0.05, pos_loss; grand totals for pos_d/neg_d.
__global__ __launch_bounds__(256)
void row_stats_kernel(const float* __restrict__ X,
                      const float* __restrict__ rowSum,
                      const float* __restrict__ rowSumSq,
                      float* __restrict__ interA,
                      float* __restrict__ threshA,
                      float* __restrict__ posLossA,
                      float* __restrict__ accum)
{
    const int i = blockIdx.x * blockDim.x + threadIdx.x;
    const float4* X4 = reinterpret_cast<const float4*>(X);
    const int cb = (i >> 3) << 3;
    const int self = i & 7;

    float acc[KCLS] = {};
    for (int q = 0; q < DIM / 4; ++q) {
        float4 xi = X4[(size_t)i * (DIM / 4) + q];
        #pragma unroll
        for (int m = 0; m < KCLS; ++m) {
            float4 xm = X4[(size_t)(cb + m) * (DIM / 4) + q];
            acc[m] = fmaf(xi.x, xm.x, acc[m]);
            acc[m] = fmaf(xi.y, xm.y, acc[m]);
            acc[m] = fmaf(xi.z, xm.z, acc[m]);
            acc[m] = fmaf(xi.w, xm.w, acc[m]);
        }
    }

    float sii = acc[self];
    float psum = 0.f, psq = 0.f, pmin = 1e30f;
    #pragma unroll
    for (int m = 0; m < KCLS; ++m) {
        if (m != self) {
            psum += acc[m];
            psq  += acc[m] * acc[m];
            pmin  = fminf(pmin, acc[m]);
        }
    }
    const float p = (float)(KCLS - 1);            // 7
    const float mneg = (float)(NROWS - KCLS);     // 4088
    float nsum = rowSum[i] - psum - sii;
    float nsq  = rowSumSq[i] - psq - sii * sii;
    float pmean = psum / p;
    float pstd  = sqrtf(fmaxf(psq / p - pmean * pmean, 0.f));
    float nmean = nsum / mneg;
    float nstd  = sqrtf(fmaxf(nsq / mneg - nmean * nmean, 0.f));
    float inter = 0.8f * (nstd * pmean + pstd * nmean) / (pstd + nstd) + 0.1f;

    float pl = 0.f;
    #pragma unroll
    for (int m = 0; m < KCLS; ++m) {
        if (m != self) pl += softplus_fast(-10.f * (acc[m] - inter));
    }
    pl *= 0.2f / p;

    interA[i]   = inter;
    threshA[i]  = pmin - 0.05f;
    posLossA[i] = pl;

    float w0 = psum, w1 = nsum;
    #pragma unroll
    for (int off = 32; off > 0; off >>= 1) {
        w0 += __shfl_down(w0, off);
        w1 += __shfl_down(w1, off);
    }
    if ((threadIdx.x & 63) == 0) {
        atomicAdd(&accum[0], w0);
        atomicAdd(&accum[1], w1);
    }
}

__global__ __launch_bounds__(256)
void finalize_kernel(const float* __restrict__ posLossA,
                     const float* __restrict__ nlsA,
                     const int* __restrict__ cntA,
                     const float* __restrict__ accum,
                     float* __restrict__ out)
{
    const int t = threadIdx.x;
    float loss = 0.f, inv = 0.f;
    for (int r = t; r < NROWS; r += 256) {
        int c = cntA[r];
        if (c > 0) loss += posLossA[r] + 0.05f * nlsA[r] / (float)c;
        else inv += 1.f;
    }
    #pragma unroll
    for (int off = 32; off > 0; off >>= 1) {
        loss += __shfl_down(loss, off);
        inv  += __shfl_down(inv, off);
    }
    __shared__ float sl[4], si[4];
    int w = t >> 6;
    if ((t & 63) == 0) { sl[w] = loss; si[w] = inv; }
    __syncthreads();
    if (t == 0) {
        float L = sl[0] + sl[1] + sl[2] + sl[3];
        float I = si[0] + si[1] + si[2] + si[3];
        out[0] = L / (float)NROWS;
        out[1] = I / (float)NROWS;
        out[2] = accum[0] / ((float)NROWS * (float)(KCLS - 1));
        out[3] = accum[1] / ((float)NROWS * (float)(NROWS - KCLS));
    }
}

extern "C" void kernel_launch(void* const* d_in, const int* in_sizes, int n_in,
                              void* d_out, int out_size, void* d_ws, size_t ws_size,
                              hipStream_t stream)
{
    const float* X = (const float*)d_in[0];

    float* ws       = (float*)d_ws;
    float* accum    = ws;                          // 8
    float* rowSum   = ws + 8;                      // 4096
    float* rowSumSq = ws + 8 + NROWS;              // 4096
    float* nlsA     = ws + 8 + 2 * NROWS;          // 4096
    int*   cntA     = (int*)(ws + 8 + 3 * NROWS);  // 4096
    float* interA   = ws + 8 + 4 * NROWS;          // 4096
    float* threshA  = ws + 8 + 5 * NROWS;          // 4096
    float* posLossA = ws + 8 + 6 * NROWS;          // 4096
    unsigned short* Xb = (unsigned short*)(ws + 8 + 7 * NROWS);  // 4096*256 bf16 = 2 MB
    // total ws use: ~2.12 MB

    // zero atomic-accumulated region: accum + rowSum + rowSumSq + nls + cnt
    (void)hipMemsetAsync(d_ws, 0, (8 + 4 * NROWS) * sizeof(float), stream);

    convert_kernel<<<(NROWS * DIM / 8) / 256, 256, 0, stream>>>(X, Xb);

    dim3 grid(NROWS / 32, 4);   // 128 x 4 blocks, 4 waves/block -> 16 j-slices
    sim_mfma_kernel<1><<<grid, 256, 0, stream>>>(Xb, rowSum, rowSumSq,
                                                 nullptr, nullptr, nullptr, nullptr);
    row_stats_kernel<<<NROWS / 256, 256, 0, stream>>>(X, rowSum, rowSumSq,
                                                      interA, threshA, posLossA, accum);
    sim_mfma_kernel<2><<<grid, 256, 0, stream>>>(Xb, rowSum, rowSumSq,
                                                 interA, threshA, nlsA, cntA);
    finalize_kernel<<<1, 256, 0, stream>>>(posLossA, nlsA, cntA, accum, (float*)d_out);
}

// Round 4
// 152.688 us; speedup vs baseline: 3.5752x; 1.1321x over previous
//
#include <hip/hip_runtime.h>
#include <math.h>

// MarginDevianceLoss: N=4096 rows, D=256, K=8 instances/class, targets = i/8.
// Outputs: [loss, prec, pos_d, neg_d] fp32.
//
// R4: sim sweep restructured for occupancy + locality:
//  - block = 4 waves x 32 rows = 128 i-rows, all waves share one 128-col
//    j-slice (B fragments identical across waves -> L1 hits).
//  - grid (32, 32) = 1024 blocks = 4096 waves = 16 waves/CU.
//  - explicit double-buffered B fragments (loads overlap MFMA + epilogue).
//  - pass 1 captures the 8 class sims per row (diagonal blocks) ->
//    row_stats needs no dot products.

#define NROWS 4096
#define DIM   256
#define KCLS  8

typedef __bf16 bf16x8 __attribute__((ext_vector_type(8)));
typedef float  f32x4  __attribute__((ext_vector_type(4)));

__device__ __forceinline__ float softplus_fast(float z) {
    // log(1+exp(z)), stable; v_exp_f32/v_log_f32
    float m = fmaxf(z, 0.f);
    float e = __builtin_exp2f(-fabsf(z) * 1.4426950408889634f);
    return m + 0.6931471805599453f * __builtin_log2f(1.f + e);
}

__device__ __forceinline__ unsigned int pack_bf2(float a, float b) {
    unsigned int ua = __float_as_uint(a);
    unsigned int ub = __float_as_uint(b);
    ua = (ua + 0x7FFFu + ((ua >> 16) & 1u)) >> 16;   // RNE
    ub = (ub + 0x7FFFu + ((ub >> 16) & 1u)) >> 16;
    return ua | (ub << 16);
}

__global__ __launch_bounds__(256)
void convert_kernel(const float* __restrict__ X, unsigned short* __restrict__ Xb)
{
    int t = blockIdx.x * 256 + threadIdx.x;          // 131072 threads x 8 elems
    const float4* X4 = reinterpret_cast<const float4*>(X);
    float4 v0 = X4[2 * t];
    float4 v1 = X4[2 * t + 1];
    uint4 o;
    o.x = pack_bf2(v0.x, v0.y);
    o.y = pack_bf2(v0.z, v0.w);
    o.z = pack_bf2(v1.x, v1.y);
    o.w = pack_bf2(v1.z, v1.w);
    reinterpret_cast<uint4*>(Xb)[t] = o;
}

// Block: 4 waves, wave w -> rows [bx*128 + w*32, +32) (2 MFMA i-tiles,
// A register-cached for full K=256). All waves sweep the same j-slice
// [by*128, +128) = 8 j-tiles of 16 cols.
// PASS 1: row sum / sumsq (unmasked) + classSim capture on diagonal.
// PASS 2: hard-negative filter + softplus accumulation.
template<int PASS>
__global__ __launch_bounds__(256)
void sim_mfma_kernel(const unsigned short* __restrict__ Xb,
                     float* __restrict__ rowSum,
                     float* __restrict__ rowSumSq,
                     float* __restrict__ classSim,
                     const float* __restrict__ interA,
                     const float* __restrict__ threshA,
                     float* __restrict__ nlsA,
                     int* __restrict__ cntA)
{
    const int lane = threadIdx.x & 63;
    const int wave = threadIdx.x >> 6;
    const int quad = lane >> 4;
    const int n16  = lane & 15;
    const int i0   = blockIdx.x * 128 + wave * 32;
    const int j0   = blockIdx.y * 128;

    // ---- A fragments: 2 i-tiles x 8 k-frags, straight from global ----
    // A[m=lane&15][k=quad*8+e]  -> 16 B contiguous per lane
    bf16x8 afrag[2][8];
    #pragma unroll
    for (int t = 0; t < 2; ++t) {
        const unsigned short* ap = Xb + (size_t)(i0 + t * 16 + n16) * DIM + quad * 8;
        #pragma unroll
        for (int kf = 0; kf < 8; ++kf)
            afrag[t][kf] = *reinterpret_cast<const bf16x8*>(ap + kf * 32);
    }

    float sI[2][4]  = {};
    float sqI[2][4] = {};
    int   cnt[2][4] = {};
    float nls[2][4] = {};
    float interR[2][4], threshR[2][4];
    if constexpr (PASS == 2) {
        #pragma unroll
        for (int t = 0; t < 2; ++t)
            #pragma unroll
            for (int r = 0; r < 4; ++r) {
                int i = i0 + t * 16 + quad * 4 + r;
                interR[t][r]  = interA[i];
                threshR[t][r] = threshA[i];
            }
    }

    // ---- j sweep, double-buffered B fragments ----
    // B[k=quad*8+e][n=lane&15] = Xb[j][k] -> 16 B contiguous per lane
    bf16x8 bcur[8], bnxt[8];
    {
        const unsigned short* bp = Xb + (size_t)(j0 + n16) * DIM + quad * 8;
        #pragma unroll
        for (int kf = 0; kf < 8; ++kf)
            bcur[kf] = *reinterpret_cast<const bf16x8*>(bp + kf * 32);
    }

    for (int jt = 0; jt < 8; ++jt) {
        if (jt < 7) {
            const unsigned short* bp = Xb + (size_t)(j0 + (jt + 1) * 16 + n16) * DIM + quad * 8;
            #pragma unroll
            for (int kf = 0; kf < 8; ++kf)
                bnxt[kf] = *reinterpret_cast<const bf16x8*>(bp + kf * 32);
        }

        f32x4 ac[2] = {{0.f, 0.f, 0.f, 0.f}, {0.f, 0.f, 0.f, 0.f}};
        #pragma unroll
        for (int kf = 0; kf < 8; ++kf) {
            ac[0] = __builtin_amdgcn_mfma_f32_16x16x32_bf16(afrag[0][kf], bcur[kf], ac[0], 0, 0, 0);
            ac[1] = __builtin_amdgcn_mfma_f32_16x16x32_bf16(afrag[1][kf], bcur[kf], ac[1], 0, 0, 0);
        }

        // C/D: col = lane&15 (j), row = quad*4 + reg (i)
        const int j = j0 + jt * 16 + n16;
        #pragma unroll
        for (int t = 0; t < 2; ++t) {
            #pragma unroll
            for (int r = 0; r < 4; ++r) {
                float s = ac[t][r];
                int i = i0 + t * 16 + quad * 4 + r;
                if constexpr (PASS == 1) {
                    sI[t][r]  += s;
                    sqI[t][r] += s * s;
                    if (((i ^ j) >> 3) == 0)               // same class (incl self)
                        classSim[i * KCLS + (j & 7)] = s;
                } else {
                    if (((i ^ j) >> 3) != 0 && s > threshR[t][r]) {
                        cnt[t][r] += 1;
                        nls[t][r] += softplus_fast(40.f * (s - interR[t][r]));
                    }
                }
            }
        }

        #pragma unroll
        for (int kf = 0; kf < 8; ++kf) bcur[kf] = bnxt[kf];
    }

    // ---- reduce across the 16 lanes of each quad (same rows), then atomics ----
    #pragma unroll
    for (int t = 0; t < 2; ++t) {
        #pragma unroll
        for (int r = 0; r < 4; ++r) {
            if constexpr (PASS == 1) {
                float a = sI[t][r], b = sqI[t][r];
                #pragma unroll
                for (int m = 8; m >= 1; m >>= 1) {
                    a += __shfl_xor(a, m);
                    b += __shfl_xor(b, m);
                }
                if (n16 == 0) {
                    int i = i0 + t * 16 + quad * 4 + r;
                    atomicAdd(&rowSum[i], a);
                    atomicAdd(&rowSumSq[i], b);
                }
            } else {
                int   c = cnt[t][r];
                float v = nls[t][r];
                #pragma unroll
                for (int m = 8; m >= 1; m >>= 1) {
                    c += __shfl_xor(c, m);
                    v += __shfl_xor(v, m);
                }
                if (n16 == 0) {
                    int i = i0 + t * 16 + quad * 4 + r;
                    if (c) {
                        atomicAdd(&cntA[i], c);
                        atomicAdd(&nlsA[i], v);
                    }
                }
            }
        }
    }
}

// Per-row stats from classSim (no dot products): pos stats, neg stats by
// subtraction, inter, thresh = pos_min - 0.05, pos_loss; grand totals.
__global__ __launch_bounds__(256)
void row_stats_kernel(const float* __restrict__ classSim,
                      const float* __restrict__ rowSum,
                      const float* __restrict__ rowSumSq,
                      float* __restrict__ interA,
                      float* __restrict__ threshA,
                      float* __restrict__ posLossA,
                      float* __restrict__ accum)
{
    const int i = blockIdx.x * blockDim.x + threadIdx.x;
    const int self = i & 7;

    float4 c0 = reinterpret_cast<const float4*>(classSim)[i * 2];
    float4 c1 = reinterpret_cast<const float4*>(classSim)[i * 2 + 1];
    float cs[KCLS] = {c0.x, c0.y, c0.z, c0.w, c1.x, c1.y, c1.z, c1.w};

    float sii = cs[self];
    float psum = 0.f, psq = 0.f, pmin = 1e30f;
    #pragma unroll
    for (int m = 0; m < KCLS; ++m) {
        if (m != self) {
            psum += cs[m];
            psq  += cs[m] * cs[m];
            pmin  = fminf(pmin, cs[m]);
        }
    }
    const float p = (float)(KCLS - 1);            // 7
    const float mneg = (float)(NROWS - KCLS);     // 4088
    float nsum = rowSum[i] - psum - sii;
    float nsq  = rowSumSq[i] - psq - sii * sii;
    float pmean = psum / p;
    float pstd  = sqrtf(fmaxf(psq / p - pmean * pmean, 0.f));
    float nmean = nsum / mneg;
    float nstd  = sqrtf(fmaxf(nsq / mneg - nmean * nmean, 0.f));
    float inter = 0.8f * (nstd * pmean + pstd * nmean) / (pstd + nstd) + 0.1f;

    float pl = 0.f;
    #pragma unroll
    for (int m = 0; m < KCLS; ++m) {
        if (m != self) pl += softplus_fast(-10.f * (cs[m] - inter));
    }
    pl *= 0.2f / p;

    interA[i]   = inter;
    threshA[i]  = pmin - 0.05f;
    posLossA[i] = pl;

    float w0 = psum, w1 = nsum;
    #pragma unroll
    for (int off = 32; off > 0; off >>= 1) {
        w0 += __shfl_down(w0, off);
        w1 += __shfl_down(w1, off);
    }
    if ((threadIdx.x & 63) == 0) {
        atomicAdd(&accum[0], w0);
        atomicAdd(&accum[1], w1);
    }
}

__global__ __launch_bounds__(256)
void finalize_kernel(const float* __restrict__ posLossA,
                     const float* __restrict__ nlsA,
                     const int* __restrict__ cntA,
                     const float* __restrict__ accum,
                     float* __restrict__ out)
{
    const int t = threadIdx.x;
    float loss = 0.f, inv = 0.f;
    for (int r = t; r < NROWS; r += 256) {
        int c = cntA[r];
        if (c > 0) loss += posLossA[r] + 0.05f * nlsA[r] / (float)c;
        else inv += 1.f;
    }
    #pragma unroll
    for (int off = 32; off > 0; off >>= 1) {
        loss += __shfl_down(loss, off);
        inv  += __shfl_down(inv, off);
    }
    __shared__ float sl[4], si[4];
    int w = t >> 6;
    if ((t & 63) == 0) { sl[w] = loss; si[w] = inv; }
    __syncthreads();
    if (t == 0) {
        float L = sl[0] + sl[1] + sl[2] + sl[3];
        float I = si[0] + si[1] + si[2] + si[3];
        out[0] = L / (float)NROWS;
        out[1] = I / (float)NROWS;
        out[2] = accum[0] / ((float)NROWS * (float)(KCLS - 1));
        out[3] = accum[1] / ((float)NROWS * (float)(NROWS - KCLS));
    }
}

extern "C" void kernel_launch(void* const* d_in, const int* in_sizes, int n_in,
                              void* d_out, int out_size, void* d_ws, size_t ws_size,
                              hipStream_t stream)
{
    const float* X = (const float*)d_in[0];

    float* ws       = (float*)d_ws;
    float* accum    = ws;                          // 8
    float* rowSum   = ws + 8;                      // 4096
    float* rowSumSq = ws + 8 + NROWS;              // 4096
    float* nlsA     = ws + 8 + 2 * NROWS;          // 4096
    int*   cntA     = (int*)(ws + 8 + 3 * NROWS);  // 4096
    float* interA   = ws + 8 + 4 * NROWS;          // 4096
    float* threshA  = ws + 8 + 5 * NROWS;          // 4096
    float* posLossA = ws + 8 + 6 * NROWS;          // 4096
    float* classSim = ws + 8 + 7 * NROWS;          // 4096*8 = 32768 (128 KB)
    unsigned short* Xb = (unsigned short*)(ws + 8 + 7 * NROWS + NROWS * KCLS);  // 2 MB
    // total ws use: ~2.25 MB

    // zero atomic-accumulated region: accum + rowSum + rowSumSq + nls + cnt
    (void)hipMemsetAsync(d_ws, 0, (8 + 4 * NROWS) * sizeof(float), stream);

    convert_kernel<<<(NROWS * DIM / 8) / 256, 256, 0, stream>>>(X, Xb);

    dim3 grid(NROWS / 128, 32);   // 32 x 32 = 1024 blocks, 4 waves each
    sim_mfma_kernel<1><<<grid, 256, 0, stream>>>(Xb, rowSum, rowSumSq, classSim,
                                                 nullptr, nullptr, nullptr, nullptr);
    row_stats_kernel<<<NROWS / 256, 256, 0, stream>>>(classSim, rowSum, rowSumSq,
                                                      interA, threshA, posLossA, accum);
    sim_mfma_kernel<2><<<grid, 256, 0, stream>>>(Xb, rowSum, rowSumSq, classSim,
                                                 interA, threshA, nlsA, cntA);
    finalize_kernel<<<1, 256, 0, stream>>>(posLossA, nlsA, cntA, accum, (float*)d_out);
}

// Round 5
// 129.421 us; speedup vs baseline: 4.2179x; 1.1798x over previous
//
#include <hip/hip_runtime.h>
#include <hip/hip_bf16.h>
#include <math.h>

// MarginDevianceLoss: N=4096, D=256, K=8, targets = i/8.
// Outputs: [loss, prec, pos_d, neg_d] fp32.
//
// R5: single bf16-MFMA GEMM materializes sim (bf16, 32 MB, symmetric-store
// trick: element (i,j) stored at j*4096+i is still row-major sim). classSim
// capture only on diagonal blocks (uniform branch). Pass 2 = flat streaming
// sweep (one block per row) that also computes row stats inline. 4 dispatches.

#define NROWS 4096
#define DIM   256
#define KCLS  8

typedef __bf16 bf16x8 __attribute__((ext_vector_type(8)));
typedef float  f32x4  __attribute__((ext_vector_type(4)));

__device__ __forceinline__ float softplus_fast(float z) {
    float m = fmaxf(z, 0.f);
    float e = __builtin_exp2f(-fabsf(z) * 1.4426950408889634f);
    return m + 0.6931471805599453f * __builtin_log2f(1.f + e);
}

__device__ __forceinline__ unsigned int pack_bf2(float a, float b) {
    unsigned int ua = __float_as_uint(a);
    unsigned int ub = __float_as_uint(b);
    ua = (ua + 0x7FFFu + ((ua >> 16) & 1u)) >> 16;   // RNE
    ub = (ub + 0x7FFFu + ((ub >> 16) & 1u)) >> 16;
    return ua | (ub << 16);
}

// Converts X (fp32) -> Xb (bf16) and zeroes the atomic accumulators
// (rowSum+rowSumSq = 8192 floats at ws[0..]).
__global__ __launch_bounds__(256)
void convert_kernel(const float* __restrict__ X, unsigned short* __restrict__ Xb,
                    float* __restrict__ zeroRegion)
{
    int t = blockIdx.x * 256 + threadIdx.x;          // 131072 threads x 8 elems
    if (t < 1024) {
        uint4 z = {0u, 0u, 0u, 0u};
        reinterpret_cast<uint4*>(zeroRegion)[2 * t]     = z;
        reinterpret_cast<uint4*>(zeroRegion)[2 * t + 1] = z;
    }
    const float4* X4 = reinterpret_cast<const float4*>(X);
    float4 v0 = X4[2 * t];
    float4 v1 = X4[2 * t + 1];
    uint4 o;
    o.x = pack_bf2(v0.x, v0.y);
    o.y = pack_bf2(v0.z, v0.w);
    o.z = pack_bf2(v1.x, v1.y);
    o.w = pack_bf2(v1.z, v1.w);
    reinterpret_cast<uint4*>(Xb)[t] = o;
}

// Block: 4 waves; wave w -> rows [bx*128+w*32, +32) (2 MFMA i-tiles, A
// register-cached for K=256). All waves sweep j-slice [by*128,+128) (8
// j-tiles), ping-pong B buffers. Accumulates rowSum/rowSumSq, stores sim
// as bf16 at (j*4096+i) [= row-major sim by symmetry], captures classSim
// on diagonal blocks only.
__global__ __launch_bounds__(256)
void gemm_kernel(const unsigned short* __restrict__ Xb,
                 float* __restrict__ rowSum,
                 float* __restrict__ rowSumSq,
                 float* __restrict__ classSim,
                 unsigned short* __restrict__ simB)
{
    const int lane = threadIdx.x & 63;
    const int wave = threadIdx.x >> 6;
    const int quad = lane >> 4;
    const int n16  = lane & 15;
    const int i0   = blockIdx.x * 128 + wave * 32;
    const int j0   = blockIdx.y * 128;
    const bool diag = (blockIdx.x == blockIdx.y);

    // A fragments: A[m=lane&15][k=quad*8+e] -> 16 B contiguous per lane
    bf16x8 afrag[2][8];
    #pragma unroll
    for (int t = 0; t < 2; ++t) {
        const unsigned short* ap = Xb + (size_t)(i0 + t * 16 + n16) * DIM + quad * 8;
        #pragma unroll
        for (int kf = 0; kf < 8; ++kf)
            afrag[t][kf] = *reinterpret_cast<const bf16x8*>(ap + kf * 32);
    }

    float sI[2][4]  = {};
    float sqI[2][4] = {};

    // sim store base (elements): (j0+n16)*4096 + i0 + quad*4 (+16 for tile 1)
    unsigned short* sp0 = simB + (((size_t)(j0 + n16)) << 12) + i0 + quad * 4;

    bf16x8 bA[8], bB[8];

    auto loadB = [&](bf16x8* bf, int jt) {
        const unsigned short* bp = Xb + (size_t)(j0 + jt * 16 + n16) * DIM + quad * 8;
        #pragma unroll
        for (int kf = 0; kf < 8; ++kf)
            bf[kf] = *reinterpret_cast<const bf16x8*>(bp + kf * 32);
    };

    auto tile = [&](const bf16x8* bf, int jt) {
        f32x4 ac[2] = {{0.f, 0.f, 0.f, 0.f}, {0.f, 0.f, 0.f, 0.f}};
        #pragma unroll
        for (int kf = 0; kf < 8; ++kf) {
            ac[0] = __builtin_amdgcn_mfma_f32_16x16x32_bf16(afrag[0][kf], bf[kf], ac[0], 0, 0, 0);
            ac[1] = __builtin_amdgcn_mfma_f32_16x16x32_bf16(afrag[1][kf], bf[kf], ac[1], 0, 0, 0);
        }
        const size_t joff = ((size_t)jt << 16);     // jt*16*4096 elements
        #pragma unroll
        for (int t = 0; t < 2; ++t) {
            #pragma unroll
            for (int r = 0; r < 4; ++r) {
                float s = ac[t][r];
                sI[t][r]  += s;
                sqI[t][r] += s * s;
            }
            uint2 pk;
            pk.x = pack_bf2(ac[t][0], ac[t][1]);
            pk.y = pack_bf2(ac[t][2], ac[t][3]);
            *reinterpret_cast<uint2*>(sp0 + joff + t * 16) = pk;
        }
        if (diag) {            // wave-uniform: only 32/1024 blocks
            int j = j0 + jt * 16 + n16;
            #pragma unroll
            for (int t = 0; t < 2; ++t)
                #pragma unroll
                for (int r = 0; r < 4; ++r) {
                    int i = i0 + t * 16 + quad * 4 + r;
                    if (((i ^ j) >> 3) == 0)
                        classSim[i * KCLS + (j & 7)] = ac[t][r];
                }
        }
    };

    loadB(bA, 0);
    #pragma unroll 1
    for (int jp = 0; jp < 4; ++jp) {
        loadB(bB, 2 * jp + 1);
        tile(bA, 2 * jp);
        if (jp < 3) loadB(bA, 2 * jp + 2);
        tile(bB, 2 * jp + 1);
    }

    // reduce across the 16 lanes of each quad (same rows), then atomics
    #pragma unroll
    for (int t = 0; t < 2; ++t) {
        #pragma unroll
        for (int r = 0; r < 4; ++r) {
            float a = sI[t][r], b = sqI[t][r];
            #pragma unroll
            for (int m = 8; m >= 1; m >>= 1) {
                a += __shfl_xor(a, m);
                b += __shfl_xor(b, m);
            }
            if (n16 == 0) {
                int i = i0 + t * 16 + quad * 4 + r;
                atomicAdd(&rowSum[i], a);
                atomicAdd(&rowSumSq[i], b);
            }
        }
    }
}

// One block per row: compute row stats inline from classSim/rowSum, then
// stream the bf16 sim row applying hard-negative filter + softplus.
__global__ __launch_bounds__(256)
void sweep_kernel(const unsigned short* __restrict__ simB,
                  const float* __restrict__ classSim,
                  const float* __restrict__ rowSum,
                  const float* __restrict__ rowSumSq,
                  float* __restrict__ rowLoss,
                  int* __restrict__ rowCnt,
                  float* __restrict__ rowPsum,
                  float* __restrict__ rowNsum)
{
    const int r = blockIdx.x;
    const int t = threadIdx.x;
    const int self = r & 7;
    const int rcls = r >> 3;

    // per-row stats (redundant per thread; broadcast loads)
    float4 c0 = reinterpret_cast<const float4*>(classSim)[r * 2];
    float4 c1 = reinterpret_cast<const float4*>(classSim)[r * 2 + 1];
    float cs[KCLS] = {c0.x, c0.y, c0.z, c0.w, c1.x, c1.y, c1.z, c1.w};

    float sii = cs[self];
    float psum = 0.f, psq = 0.f, pmin = 1e30f;
    #pragma unroll
    for (int m = 0; m < KCLS; ++m) {
        if (m != self) {
            psum += cs[m];
            psq  += cs[m] * cs[m];
            pmin  = fminf(pmin, cs[m]);
        }
    }
    const float p = (float)(KCLS - 1);            // 7
    const float mneg = (float)(NROWS - KCLS);     // 4088
    float nsum = rowSum[r] - psum - sii;
    float nsq  = rowSumSq[r] - psq - sii * sii;
    float pmean = psum / p;
    float pstd  = sqrtf(fmaxf(psq / p - pmean * pmean, 0.f));
    float nmean = nsum / mneg;
    float nstd  = sqrtf(fmaxf(nsq / mneg - nmean * nmean, 0.f));
    float inter  = 0.8f * (nstd * pmean + pstd * nmean) / (pstd + nstd) + 0.1f;
    float thresh = pmin - 0.05f;

    float posLoss = 0.f;
    #pragma unroll
    for (int m = 0; m < KCLS; ++m) {
        if (m != self) posLoss += softplus_fast(-10.f * (cs[m] - inter));
    }
    posLoss *= 0.2f / p;

    // stream 16 elements of this row (bf16 -> f32 via <<16)
    const uint4* row = reinterpret_cast<const uint4*>(simB + ((size_t)r << 12));
    uint4 u0 = row[2 * t];
    uint4 u1 = row[2 * t + 1];
    unsigned int w[8] = {u0.x, u0.y, u0.z, u0.w, u1.x, u1.y, u1.z, u1.w};
    float cnt = 0.f, nls = 0.f;
    const int jb = t * 16;
    #pragma unroll
    for (int d = 0; d < 8; ++d) {
        float slo = __uint_as_float(w[d] << 16);
        float shi = __uint_as_float(w[d] & 0xffff0000u);
        int jl = jb + 2 * d, jh = jl + 1;
        if (((jl >> 3) != rcls) && slo > thresh) {
            cnt += 1.f;
            nls += softplus_fast(40.f * (slo - inter));
        }
        if (((jh >> 3) != rcls) && shi > thresh) {
            cnt += 1.f;
            nls += softplus_fast(40.f * (shi - inter));
        }
    }

    // block-reduce cnt, nls
    #pragma unroll
    for (int off = 32; off > 0; off >>= 1) {
        cnt += __shfl_down(cnt, off);
        nls += __shfl_down(nls, off);
    }
    __shared__ float sc[4], sn[4];
    if ((t & 63) == 0) { sc[t >> 6] = cnt; sn[t >> 6] = nls; }
    __syncthreads();
    if (t == 0) {
        float C = sc[0] + sc[1] + sc[2] + sc[3];
        float L = sn[0] + sn[1] + sn[2] + sn[3];
        int ci = (int)C;                  // exact (counts are small ints)
        rowCnt[r]  = ci;
        rowPsum[r] = psum;
        rowNsum[r] = nsum;
        rowLoss[r] = (ci > 0) ? (posLoss + 0.05f * L / C) : 0.f;
    }
}

__global__ __launch_bounds__(256)
void finalize_kernel(const float* __restrict__ rowLoss,
                     const int* __restrict__ rowCnt,
                     const float* __restrict__ rowPsum,
                     const float* __restrict__ rowNsum,
                     float* __restrict__ out)
{
    const int t = threadIdx.x;
    float loss = 0.f, inv = 0.f, pd = 0.f, nd = 0.f;
    for (int r = t; r < NROWS; r += 256) {
        loss += rowLoss[r];
        inv  += (rowCnt[r] == 0) ? 1.f : 0.f;
        pd   += rowPsum[r];
        nd   += rowNsum[r];
    }
    #pragma unroll
    for (int off = 32; off > 0; off >>= 1) {
        loss += __shfl_down(loss, off);
        inv  += __shfl_down(inv, off);
        pd   += __shfl_down(pd, off);
        nd   += __shfl_down(nd, off);
    }
    __shared__ float sl[4], si[4], sp[4], sq[4];
    int w = t >> 6;
    if ((t & 63) == 0) { sl[w] = loss; si[w] = inv; sp[w] = pd; sq[w] = nd; }
    __syncthreads();
    if (t == 0) {
        float L = sl[0] + sl[1] + sl[2] + sl[3];
        float I = si[0] + si[1] + si[2] + si[3];
        float P = sp[0] + sp[1] + sp[2] + sp[3];
        float Nn = sq[0] + sq[1] + sq[2] + sq[3];
        out[0] = L / (float)NROWS;
        out[1] = I / (float)NROWS;
        out[2] = P / ((float)NROWS * (float)(KCLS - 1));
        out[3] = Nn / ((float)NROWS * (float)(NROWS - KCLS));
    }
}

extern "C" void kernel_launch(void* const* d_in, const int* in_sizes, int n_in,
                              void* d_out, int out_size, void* d_ws, size_t ws_size,
                              hipStream_t stream)
{
    const float* X = (const float*)d_in[0];

    float* ws       = (float*)d_ws;
    float* rowSum   = ws;                          // 4096  (zeroed by convert)
    float* rowSumSq = ws + NROWS;                  // 4096  (zeroed by convert)
    float* classSim = ws + 2 * NROWS;              // 32768 (fully written by diag blocks)
    float* rowLoss  = ws + 2 * NROWS + NROWS * KCLS;          // 4096
    float* rowPsum  = rowLoss + NROWS;             // 4096
    float* rowNsum  = rowPsum + NROWS;             // 4096
    int*   rowCnt   = (int*)(rowNsum + NROWS);     // 4096
    unsigned short* Xb   = (unsigned short*)(rowCnt + NROWS);        // 2 MB
    unsigned short* simB = Xb + (size_t)NROWS * DIM;                 // 32 MB
    // total ws use: ~36 MB

    convert_kernel<<<(NROWS * DIM / 8) / 256, 256, 0, stream>>>(X, Xb, rowSum);

    dim3 grid(NROWS / 128, 32);   // 32 x 32 = 1024 blocks, 4 waves each
    gemm_kernel<<<grid, 256, 0, stream>>>(Xb, rowSum, rowSumSq, classSim, simB);

    sweep_kernel<<<NROWS, 256, 0, stream>>>(simB, classSim, rowSum, rowSumSq,
                                            rowLoss, rowCnt, rowPsum, rowNsum);

    finalize_kernel<<<1, 256, 0, stream>>>(rowLoss, rowCnt, rowPsum, rowNsum,
                                           (float*)d_out);
}

// Round 6
// 106.716 us; speedup vs baseline: 5.1153x; 1.2128x over previous
//
#include <hip/hip_runtime.h>
#include <math.h>

// MarginDevianceLoss: N=4096, D=256, K=8, targets = i/8.
// Outputs: [loss, prec, pos_d, neg_d] fp32.
//
// R6: - Xf fragment-major bf16 layout: frag(tile16,kf)[lane] contiguous ->
//       every MFMA A/B fragment load is a coalesced 1-KB global_load_dwordx4.
//     - GEMM is pure: load frags, MFMA, pack bf16, store sim (symmetric-store
//       at j*4096+i keeps sim row-major). No stats, no atomics.
//     - Sweep (one block per row) loads the 8-KB bf16 row once into registers:
//       pass A = sum/sumsq/class-extract -> row stats (inter/thresh) in-block;
//       pass B = hard-negative filter + softplus. Writes rowLoss/Cnt/Psum/Nsum.
//     - finalize reduces 4096 rows -> 4 outputs. No zero-init needed anywhere.

#define NROWS 4096
#define DIM   256
#define KCLS  8

typedef __bf16 bf16x8 __attribute__((ext_vector_type(8)));
typedef float  f32x4  __attribute__((ext_vector_type(4)));

__device__ __forceinline__ float softplus_fast(float z) {
    float m = fmaxf(z, 0.f);
    float e = __builtin_exp2f(-fabsf(z) * 1.4426950408889634f);
    return m + 0.6931471805599453f * __builtin_log2f(1.f + e);
}

__device__ __forceinline__ unsigned int pack_bf2(float a, float b) {
    unsigned int ua = __float_as_uint(a);
    unsigned int ub = __float_as_uint(b);
    ua = (ua + 0x7FFFu + ((ua >> 16) & 1u)) >> 16;   // RNE
    ub = (ub + 0x7FFFu + ((ub >> 16) & 1u)) >> 16;
    return ua | (ub << 16);
}

// X (fp32 row-major) -> Xf (bf16 fragment-major):
// Xf[((tile*8 + kf)*64 + lane)*8 + e] = X[tile*16 + (lane&15)][kf*32 + (lane>>4)*8 + e]
__global__ __launch_bounds__(256)
void convert_kernel(const float* __restrict__ X, unsigned short* __restrict__ Xf)
{
    int v = blockIdx.x * 256 + threadIdx.x;    // 131072 fragments-slices of 16 B
    int tile = v >> 9;
    int kf   = (v >> 6) & 7;
    int lane = v & 63;
    int row  = tile * 16 + (lane & 15);
    int c4   = kf * 8 + (lane >> 4) * 2;       // col/4
    const float4* X4 = reinterpret_cast<const float4*>(X);
    float4 a = X4[row * 64 + c4];
    float4 b = X4[row * 64 + c4 + 1];
    uint4 o;
    o.x = pack_bf2(a.x, a.y);
    o.y = pack_bf2(a.z, a.w);
    o.z = pack_bf2(b.x, b.y);
    o.w = pack_bf2(b.z, b.w);
    reinterpret_cast<uint4*>(Xf)[v] = o;
}

// Block: 4 waves; wave w -> i-tiles {bx*8 + w*2, +1} (32 rows, A cached in
// regs for K=256). All waves sweep j-tiles [by*8, +8) (B frags shared -> L1).
// Stores sim bf16 at (j*4096 + i)  [row-major by symmetry].
__global__ __launch_bounds__(256)
void gemm_kernel(const unsigned short* __restrict__ Xf,
                 unsigned short* __restrict__ simB)
{
    const int lane = threadIdx.x & 63;
    const int wave = threadIdx.x >> 6;
    const int quad = lane >> 4;
    const int n16  = lane & 15;
    const int it0  = blockIdx.x * 8 + wave * 2;    // first i-tile index
    const int i0   = it0 * 16;
    const int j0   = blockIdx.y * 128;
    const int jt0  = blockIdx.y * 8;

    // A fragments: 2 i-tiles x 8 k-frags, coalesced 1-KB loads
    bf16x8 afrag[2][8];
    #pragma unroll
    for (int t = 0; t < 2; ++t) {
        const unsigned short* ap = Xf + ((size_t)(it0 + t) * 8) * 512 + lane * 8;
        #pragma unroll
        for (int kf = 0; kf < 8; ++kf)
            afrag[t][kf] = *reinterpret_cast<const bf16x8*>(ap + kf * 512);
    }

    // sim store base (elements): (j0+n16)*4096 + i0 + quad*4
    unsigned short* sp0 = simB + (((size_t)(j0 + n16)) << 12) + i0 + quad * 4;

    bf16x8 bA[8], bB[8];
    auto loadB = [&](bf16x8* bf, int jt) {
        const unsigned short* bp = Xf + ((size_t)(jt0 + jt) * 8) * 512 + lane * 8;
        #pragma unroll
        for (int kf = 0; kf < 8; ++kf)
            bf[kf] = *reinterpret_cast<const bf16x8*>(bp + kf * 512);
    };
    auto tile = [&](const bf16x8* bf, int jt) {
        f32x4 ac[2] = {{0.f, 0.f, 0.f, 0.f}, {0.f, 0.f, 0.f, 0.f}};
        #pragma unroll
        for (int kf = 0; kf < 8; ++kf) {
            ac[0] = __builtin_amdgcn_mfma_f32_16x16x32_bf16(afrag[0][kf], bf[kf], ac[0], 0, 0, 0);
            ac[1] = __builtin_amdgcn_mfma_f32_16x16x32_bf16(afrag[1][kf], bf[kf], ac[1], 0, 0, 0);
        }
        const size_t joff = ((size_t)jt << 16);     // jt*16*4096 elements
        #pragma unroll
        for (int t = 0; t < 2; ++t) {
            uint2 pk;
            pk.x = pack_bf2(ac[t][0], ac[t][1]);
            pk.y = pack_bf2(ac[t][2], ac[t][3]);
            *reinterpret_cast<uint2*>(sp0 + joff + t * 16) = pk;
        }
    };

    loadB(bA, 0);
    #pragma unroll 1
    for (int jp = 0; jp < 4; ++jp) {
        loadB(bB, 2 * jp + 1);
        tile(bA, 2 * jp);
        if (jp < 3) loadB(bA, 2 * jp + 2);
        tile(bB, 2 * jp + 1);
    }
}

// One block per row r. Row (8 KB bf16) -> 16 elems/thread in registers.
// Pass A: sum/sumsq + class-col extraction -> broadcast stats via LDS.
// Pass B: filter + softplus. Writes rowLoss/rowCnt/rowPsum/rowNsum.
__global__ __launch_bounds__(256)
void sweep_kernel(const unsigned short* __restrict__ simB,
                  float* __restrict__ rowLoss,
                  int* __restrict__ rowCnt,
                  float* __restrict__ rowPsum,
                  float* __restrict__ rowNsum)
{
    const int r = blockIdx.x;
    const int t = threadIdx.x;
    const int self = r & 7;
    const int rcls = r >> 3;

    const uint4* row = reinterpret_cast<const uint4*>(simB + ((size_t)r << 12));
    uint4 u0 = row[2 * t];
    uint4 u1 = row[2 * t + 1];
    unsigned int w[8] = {u0.x, u0.y, u0.z, u0.w, u1.x, u1.y, u1.z, u1.w};

    // ---- pass A: sum & sumsq over this thread's 16 elems ----
    float s1 = 0.f, s2 = 0.f;
    #pragma unroll
    for (int d = 0; d < 8; ++d) {
        float lo = __uint_as_float(w[d] << 16);
        float hi = __uint_as_float(w[d] & 0xffff0000u);
        s1 += lo + hi;
        s2 += lo * lo + hi * hi;
    }
    // wave butterfly (all lanes get the wave total)
    #pragma unroll
    for (int m = 1; m < 64; m <<= 1) {
        s1 += __shfl_xor(s1, m);
        s2 += __shfl_xor(s2, m);
    }
    __shared__ float sS1[4], sS2[4], clsLDS[KCLS];
    if ((t & 63) == 0) { sS1[t >> 6] = s1; sS2[t >> 6] = s2; }
    // class columns [rcls*8, rcls*8+8) live entirely in one thread's 16 elems
    const int towner = rcls >> 1;              // = (rcls*8)/16
    if (t == towner) {
        const int sub = (rcls & 1) * 4;        // offset in w[] (4 uints = 8 elems)
        #pragma unroll
        for (int d = 0; d < 4; ++d) {
            clsLDS[2 * d]     = __uint_as_float(w[sub + d] << 16);
            clsLDS[2 * d + 1] = __uint_as_float(w[sub + d] & 0xffff0000u);
        }
    }
    __syncthreads();
    const float S  = sS1[0] + sS1[1] + sS1[2] + sS1[3];
    const float SQ = sS2[0] + sS2[1] + sS2[2] + sS2[3];

    // ---- per-row stats (redundant per thread; LDS broadcasts) ----
    float cs[KCLS];
    #pragma unroll
    for (int m = 0; m < KCLS; ++m) cs[m] = clsLDS[m];
    float sii = cs[self];
    float psum = 0.f, psq = 0.f, pmin = 1e30f;
    #pragma unroll
    for (int m = 0; m < KCLS; ++m) {
        if (m != self) {
            psum += cs[m];
            psq  += cs[m] * cs[m];
            pmin  = fminf(pmin, cs[m]);
        }
    }
    const float p = (float)(KCLS - 1);            // 7
    const float mneg = (float)(NROWS - KCLS);     // 4088
    float nsum = S - psum - sii;
    float nsq  = SQ - psq - sii * sii;
    float pmean = psum / p;
    float pstd  = sqrtf(fmaxf(psq / p - pmean * pmean, 0.f));
    float nmean = nsum / mneg;
    float nstd  = sqrtf(fmaxf(nsq / mneg - nmean * nmean, 0.f));
    float inter  = 0.8f * (nstd * pmean + pstd * nmean) / (pstd + nstd) + 0.1f;
    float thresh = pmin - 0.05f;

    // ---- pass B: filter + softplus over this thread's 16 elems ----
    float cnt = 0.f, nls = 0.f;
    const int jb = t * 16;
    #pragma unroll
    for (int d = 0; d < 8; ++d) {
        float lo = __uint_as_float(w[d] << 16);
        float hi = __uint_as_float(w[d] & 0xffff0000u);
        int jl = jb + 2 * d;
        if (((jl >> 3) != rcls) && lo > thresh) {
            cnt += 1.f;
            nls += softplus_fast(40.f * (lo - inter));
        }
        if ((((jl + 1) >> 3) != rcls) && hi > thresh) {
            cnt += 1.f;
            nls += softplus_fast(40.f * (hi - inter));
        }
    }
    #pragma unroll
    for (int off = 32; off > 0; off >>= 1) {
        cnt += __shfl_down(cnt, off);
        nls += __shfl_down(nls, off);
    }
    __shared__ float sc[4], sn[4];
    if ((t & 63) == 0) { sc[t >> 6] = cnt; sn[t >> 6] = nls; }
    __syncthreads();
    if (t == 0) {
        float C = sc[0] + sc[1] + sc[2] + sc[3];
        float L = sn[0] + sn[1] + sn[2] + sn[3];
        int ci = (int)C;
        float pl = 0.f;
        #pragma unroll
        for (int m = 0; m < KCLS; ++m) {
            if (m != self) pl += softplus_fast(-10.f * (cs[m] - inter));
        }
        pl *= 0.2f / p;
        rowCnt[r]  = ci;
        rowPsum[r] = psum;
        rowNsum[r] = nsum;
        rowLoss[r] = (ci > 0) ? (pl + 0.05f * L / C) : 0.f;
    }
}

__global__ __launch_bounds__(256)
void finalize_kernel(const float* __restrict__ rowLoss,
                     const int* __restrict__ rowCnt,
                     const float* __restrict__ rowPsum,
                     const float* __restrict__ rowNsum,
                     float* __restrict__ out)
{
    const int t = threadIdx.x;
    float loss = 0.f, inv = 0.f, pd = 0.f, nd = 0.f;
    for (int r = t; r < NROWS; r += 256) {
        loss += rowLoss[r];
        inv  += (rowCnt[r] == 0) ? 1.f : 0.f;
        pd   += rowPsum[r];
        nd   += rowNsum[r];
    }
    #pragma unroll
    for (int off = 32; off > 0; off >>= 1) {
        loss += __shfl_down(loss, off);
        inv  += __shfl_down(inv, off);
        pd   += __shfl_down(pd, off);
        nd   += __shfl_down(nd, off);
    }
    __shared__ float sl[4], si[4], sp[4], sq[4];
    int w = t >> 6;
    if ((t & 63) == 0) { sl[w] = loss; si[w] = inv; sp[w] = pd; sq[w] = nd; }
    __syncthreads();
    if (t == 0) {
        float L = sl[0] + sl[1] + sl[2] + sl[3];
        float I = si[0] + si[1] + si[2] + si[3];
        float P = sp[0] + sp[1] + sp[2] + sp[3];
        float Nn = sq[0] + sq[1] + sq[2] + sq[3];
        out[0] = L / (float)NROWS;
        out[1] = I / (float)NROWS;
        out[2] = P / ((float)NROWS * (float)(KCLS - 1));
        out[3] = Nn / ((float)NROWS * (float)(NROWS - KCLS));
    }
}

extern "C" void kernel_launch(void* const* d_in, const int* in_sizes, int n_in,
                              void* d_out, int out_size, void* d_ws, size_t ws_size,
                              hipStream_t stream)
{
    const float* X = (const float*)d_in[0];

    float* ws      = (float*)d_ws;
    float* rowLoss = ws;                           // 4096
    float* rowPsum = ws + NROWS;                   // 4096
    float* rowNsum = ws + 2 * NROWS;               // 4096
    int*   rowCnt  = (int*)(ws + 3 * NROWS);       // 4096
    unsigned short* Xf   = (unsigned short*)(ws + 4 * NROWS);   // 2 MB
    unsigned short* simB = Xf + (size_t)NROWS * DIM;            // 32 MB
    // total ws use: ~34.1 MB; no zero-init required (no atomics anywhere)

    convert_kernel<<<512, 256, 0, stream>>>(X, Xf);

    dim3 grid(NROWS / 128, 32);   // 32 x 32 = 1024 blocks, 4 waves each
    gemm_kernel<<<grid, 256, 0, stream>>>(Xf, simB);

    sweep_kernel<<<NROWS, 256, 0, stream>>>(simB, rowLoss, rowCnt, rowPsum, rowNsum);

    finalize_kernel<<<1, 256, 0, stream>>>(rowLoss, rowCnt, rowPsum, rowNsum,
                                           (float*)d_out);
}